// Round 1
// baseline (6070.109 us; speedup 1.0000x reference)
//
#include <hip/hip_runtime.h>
#include <math.h>

#define H_   128
#define B_   4
#define L_   2048
#define KN   24
#define M_   64
#define FF_  512
#define NROW (B_*L_*KN)   // 196608 rows
#define LKR  (L_*KN)      // 49152 rows per batch
#define TR   16           // rows per block

__device__ __forceinline__ float gelu_f(float x) {
    // exact (erf) GELU, matches jax.nn.gelu(approximate=False)
    return 0.5f * x * (1.0f + erff(x * 0.70710678118654752f));
}

__device__ __forceinline__ float wsum(float v) {
#pragma unroll
    for (int m = 32; m; m >>= 1) v += __shfl_xor(v, m, 64);
    return v;
}

// ---- micro-tiled linear helpers: A rows staged in LDS (wave-uniform b128
// broadcast reads), W streamed from global (L2-resident, ~800 KB total). ----

// 2 cols (c0, c0+64) x 4 rows (r0..r0+3), K = KD.  out[r][c] = b[c] + sum_k W[c][k]*x[r][k]
template<int KD>
__device__ __forceinline__ void lin_2c4r(
    const float* __restrict__ W, const float* __restrict__ Bb,
    float (*xin)[KD], int c0, int c1, int r0,
    float (&acc0)[4], float (&acc1)[4])
{
    const float bb0 = Bb[c0], bb1 = Bb[c1];
#pragma unroll
    for (int j = 0; j < 4; ++j) { acc0[j] = bb0; acc1[j] = bb1; }
    const float4* wa = (const float4*)(W + c0*KD);
    const float4* wb = (const float4*)(W + c1*KD);
    for (int k4 = 0; k4 < KD/4; ++k4) {
        const float4 w0 = wa[k4], w1 = wb[k4];
#pragma unroll
        for (int j = 0; j < 4; ++j) {
            const float4 a = ((const float4*)xin[r0+j])[k4];
            acc0[j] = fmaf(w0.x, a.x, acc0[j]);
            acc0[j] = fmaf(w0.y, a.y, acc0[j]);
            acc0[j] = fmaf(w0.z, a.z, acc0[j]);
            acc0[j] = fmaf(w0.w, a.w, acc0[j]);
            acc1[j] = fmaf(w1.x, a.x, acc1[j]);
            acc1[j] = fmaf(w1.y, a.y, acc1[j]);
            acc1[j] = fmaf(w1.z, a.z, acc1[j]);
            acc1[j] = fmaf(w1.w, a.w, acc1[j]);
        }
    }
}

// 4 cols (c + i*CS) x 8 rows (r0..r0+7), K = KD
template<int KD, int CS>
__device__ __forceinline__ void lin_4c8r(
    const float* __restrict__ W, const float* __restrict__ Bb,
    float (*xin)[KD], int c, int r0, float (&acc)[4][8])
{
#pragma unroll
    for (int i = 0; i < 4; ++i) {
        const float bb = Bb[c + i*CS];
#pragma unroll
        for (int j = 0; j < 8; ++j) acc[i][j] = bb;
    }
    const float4* w0 = (const float4*)(W + (size_t)(c       )*KD);
    const float4* w1 = (const float4*)(W + (size_t)(c +   CS)*KD);
    const float4* w2 = (const float4*)(W + (size_t)(c + 2*CS)*KD);
    const float4* w3 = (const float4*)(W + (size_t)(c + 3*CS)*KD);
    for (int k4 = 0; k4 < KD/4; ++k4) {
        const float4 p0 = w0[k4], p1 = w1[k4], p2 = w2[k4], p3 = w3[k4];
#pragma unroll
        for (int j = 0; j < 8; ++j) {
            const float4 a = ((const float4*)xin[r0+j])[k4];
            acc[0][j] = fmaf(p0.x,a.x,fmaf(p0.y,a.y,fmaf(p0.z,a.z,fmaf(p0.w,a.w,acc[0][j]))));
            acc[1][j] = fmaf(p1.x,a.x,fmaf(p1.y,a.y,fmaf(p1.z,a.z,fmaf(p1.w,a.w,acc[1][j]))));
            acc[2][j] = fmaf(p2.x,a.x,fmaf(p2.y,a.y,fmaf(p2.z,a.z,fmaf(p2.w,a.w,acc[2][j]))));
            acc[3][j] = fmaf(p3.x,a.x,fmaf(p3.y,a.y,fmaf(p3.z,a.z,fmaf(p3.w,a.w,acc[3][j]))));
        }
    }
}

__global__ void k_zero(float* __restrict__ dh) {
    const int i = blockIdx.x * 256 + threadIdx.x;
    if (i < B_*M_*H_) dh[i] = 0.0f;
}

__global__ void k_scale(float* __restrict__ dh, const float* __restrict__ Ys) {
    const int i = blockIdx.x * 256 + threadIdx.x;
    if (i < B_*M_*H_) dh[i] = dh[i] / Ys[i >> 7];
}

// msg = W3(gelu(W2(gelu(W1([hY,hE,hV]))))) ; scatter-add into dh[b,m,:]
__global__ __launch_bounds__(256) void k_msg1(
    const float* __restrict__ hY, const float* __restrict__ hE,
    const float* __restrict__ hV, const int* __restrict__ nn,
    const float* __restrict__ W1, const float* __restrict__ B1,
    const float* __restrict__ W2, const float* __restrict__ B2,
    const float* __restrict__ W3, const float* __restrict__ B3,
    float* __restrict__ dh)
{
    __shared__ float xs[TR][3*H_];
    __shared__ float t1s[TR][H_];
    __shared__ float t2s[TR][H_];
    const int tid = threadIdx.x;
    const int row0 = blockIdx.x * TR;
    const int b = row0 / LKR;          // constant per block (LKR % TR == 0)

    for (int i = tid; i < TR*3*H_; i += 256) {
        const int r = i / (3*H_), k = i - r*(3*H_);
        const int g = row0 + r;
        float v;
        if (k < H_)        v = hY[(size_t)g*H_ + k];
        else if (k < 2*H_) v = hE[(size_t)g*H_ + (k-H_)];
        else               v = hV[(size_t)(g/KN)*H_ + (k-2*H_)];
        xs[r][k] = v;
    }
    __syncthreads();

    const int c0 = tid & 63, c1 = c0 + 64;
    const int r0 = (tid >> 6) * 4;
    float a0[4], a1[4];

    lin_2c4r<3*H_>(W1, B1, xs, c0, c1, r0, a0, a1);
#pragma unroll
    for (int j = 0; j < 4; ++j) {
        t1s[r0+j][c0] = gelu_f(a0[j]);
        t1s[r0+j][c1] = gelu_f(a1[j]);
    }
    __syncthreads();

    lin_2c4r<H_>(W2, B2, t1s, c0, c1, r0, a0, a1);
#pragma unroll
    for (int j = 0; j < 4; ++j) {
        t2s[r0+j][c0] = gelu_f(a0[j]);
        t2s[r0+j][c1] = gelu_f(a1[j]);
    }
    __syncthreads();

    lin_2c4r<H_>(W3, B3, t2s, c0, c1, r0, a0, a1);
#pragma unroll
    for (int j = 0; j < 4; ++j) {
        const int m = nn[row0 + r0 + j];
        float* base = dh + ((size_t)(b*M_ + m))*H_;
        __hip_atomic_fetch_add(base + c0, a0[j], __ATOMIC_RELAXED, __HIP_MEMORY_SCOPE_AGENT);
        __hip_atomic_fetch_add(base + c1, a1[j], __ATOMIC_RELAXED, __HIP_MEMORY_SCOPE_AGENT);
    }
}

// h_Y = LN2( y1 + Wout(gelu(Win(y1))) ),  y1 = LN1(hY + dh[b, nn])
__global__ __launch_bounds__(256) void k_hy(
    const float* __restrict__ hY, const float* __restrict__ dh,
    const int* __restrict__ nn,
    const float* __restrict__ Win, const float* __restrict__ Bin,
    const float* __restrict__ Wout, const float* __restrict__ Bout,
    const float* __restrict__ n1s, const float* __restrict__ n1b,
    const float* __restrict__ n2s, const float* __restrict__ n2b,
    float* __restrict__ outY)
{
    __shared__ float ys[TR][H_];
    __shared__ float ff[TR][FF_];
    const int tid = threadIdx.x;
    const int row0 = blockIdx.x * TR;
    const int b = row0 / LKR;

    for (int i = tid; i < TR*H_; i += 256) {
        const int r = i >> 7, cc = i & (H_-1);
        const int g = row0 + r;
        const int m = nn[g];
        ys[r][cc] = hY[(size_t)g*H_ + cc] + dh[((size_t)(b*M_ + m))*H_ + cc];
    }
    __syncthreads();

    const int lane = tid & 63, wv = tid >> 6;
#pragma unroll
    for (int i = 0; i < TR/4; ++i) {   // LN1 in place (wave owns its 4 rows)
        const int r = wv*(TR/4) + i;
        const float v0 = ys[r][lane], v1 = ys[r][lane+64];
        const float mu = wsum(v0+v1) * (1.0f/H_);
        const float d0 = v0-mu, d1 = v1-mu;
        const float var = wsum(d0*d0 + d1*d1) * (1.0f/H_);
        const float rs = rsqrtf(var + 1e-5f);
        ys[r][lane]    = d0*rs*n1s[lane]    + n1b[lane];
        ys[r][lane+64] = d1*rs*n1s[lane+64] + n1b[lane+64];
    }
    __syncthreads();

    {   // Win: 128 -> 512, gelu
        const int c = tid & 127;
        const int r0 = (tid >> 7) * 8;
        float acc[4][8];
        lin_4c8r<H_, H_>(Win, Bin, ys, c, r0, acc);
#pragma unroll
        for (int i = 0; i < 4; ++i)
#pragma unroll
            for (int j = 0; j < 8; ++j)
                ff[r0+j][c + i*H_] = gelu_f(acc[i][j]);
    }
    __syncthreads();

    {   // Wout: 512 -> 128, residual into ys
        const int c0 = tid & 63, c1 = c0 + 64;
        const int r0 = (tid >> 6) * 4;
        float a0[4], a1[4];
        lin_2c4r<FF_>(Wout, Bout, ff, c0, c1, r0, a0, a1);
#pragma unroll
        for (int j = 0; j < 4; ++j) {
            ys[r0+j][c0] += a0[j];
            ys[r0+j][c1] += a1[j];
        }
    }
    __syncthreads();

#pragma unroll
    for (int i = 0; i < TR/4; ++i) {   // LN2 -> outY
        const int r = wv*(TR/4) + i;
        const int g = row0 + r;
        const float v0 = ys[r][lane], v1 = ys[r][lane+64];
        const float mu = wsum(v0+v1) * (1.0f/H_);
        const float d0 = v0-mu, d1 = v1-mu;
        const float var = wsum(d0*d0 + d1*d1) * (1.0f/H_);
        const float rs = rsqrtf(var + 1e-5f);
        outY[(size_t)g*H_ + lane]      = d0*rs*n2s[lane]    + n2b[lane];
        outY[(size_t)g*H_ + lane + 64] = d1*rs*n2s[lane+64] + n2b[lane+64];
    }
}

// h_E = LN3( hE + W13(gelu(W12(gelu(W11([h_Y,hE,hV]))))) )
__global__ __launch_bounds__(256) void k_he(
    const float* __restrict__ hYn, const float* __restrict__ hE,
    const float* __restrict__ hV,
    const float* __restrict__ W11, const float* __restrict__ B11,
    const float* __restrict__ W12, const float* __restrict__ B12,
    const float* __restrict__ W13, const float* __restrict__ B13,
    const float* __restrict__ n3s, const float* __restrict__ n3b,
    float* __restrict__ outE)
{
    __shared__ float xs[TR][3*H_];
    __shared__ float t1s[TR][H_];
    __shared__ float t2s[TR][H_];
    const int tid = threadIdx.x;
    const int row0 = blockIdx.x * TR;

    for (int i = tid; i < TR*3*H_; i += 256) {
        const int r = i / (3*H_), k = i - r*(3*H_);
        const int g = row0 + r;
        float v;
        if (k < H_)        v = hYn[(size_t)g*H_ + k];
        else if (k < 2*H_) v = hE[(size_t)g*H_ + (k-H_)];
        else               v = hV[(size_t)(g/KN)*H_ + (k-2*H_)];
        xs[r][k] = v;
    }
    __syncthreads();

    const int c0 = tid & 63, c1 = c0 + 64;
    const int r0 = (tid >> 6) * 4;
    float a0[4], a1[4];

    lin_2c4r<3*H_>(W11, B11, xs, c0, c1, r0, a0, a1);
#pragma unroll
    for (int j = 0; j < 4; ++j) {
        t1s[r0+j][c0] = gelu_f(a0[j]);
        t1s[r0+j][c1] = gelu_f(a1[j]);
    }
    __syncthreads();

    lin_2c4r<H_>(W12, B12, t1s, c0, c1, r0, a0, a1);
#pragma unroll
    for (int j = 0; j < 4; ++j) {
        t2s[r0+j][c0] = gelu_f(a0[j]);
        t2s[r0+j][c1] = gelu_f(a1[j]);
    }
    __syncthreads();

    lin_2c4r<H_>(W13, B13, t2s, c0, c1, r0, a0, a1);
#pragma unroll
    for (int j = 0; j < 4; ++j) {  // residual; stash pre-LN rows in t1s (free after W12)
        const int g = row0 + r0 + j;
        t1s[r0+j][c0] = hE[(size_t)g*H_ + c0] + a0[j];
        t1s[r0+j][c1] = hE[(size_t)g*H_ + c1] + a1[j];
    }
    __syncthreads();

    const int lane = tid & 63, wv = tid >> 6;
#pragma unroll
    for (int i = 0; i < TR/4; ++i) {   // LN3 -> outE
        const int r = wv*(TR/4) + i;
        const int g = row0 + r;
        const float v0 = t1s[r][lane], v1 = t1s[r][lane+64];
        const float mu = wsum(v0+v1) * (1.0f/H_);
        const float d0 = v0-mu, d1 = v1-mu;
        const float var = wsum(d0*d0 + d1*d1) * (1.0f/H_);
        const float rs = rsqrtf(var + 1e-5f);
        outE[(size_t)g*H_ + lane]    = d0*rs*n3s[lane]    + n3b[lane];
        outE[(size_t)g*H_ + lane+64] = d1*rs*n3s[lane+64] + n3b[lane+64];
    }
}

extern "C" void kernel_launch(void* const* d_in, const int* in_sizes, int n_in,
                              void* d_out, int out_size, void* d_ws, size_t ws_size,
                              hipStream_t stream) {
    const int*   nn   = (const int*)  d_in[0];
    const float* Ys   = (const float*)d_in[1];
    const float* hY   = (const float*)d_in[2];
    const float* hE   = (const float*)d_in[3];
    const float* hV   = (const float*)d_in[4];
    const float* W1w  = (const float*)d_in[5];  const float* W1b  = (const float*)d_in[6];
    const float* W2w  = (const float*)d_in[7];  const float* W2b  = (const float*)d_in[8];
    const float* W3w  = (const float*)d_in[9];  const float* W3b  = (const float*)d_in[10];
    const float* W11w = (const float*)d_in[11]; const float* W11b = (const float*)d_in[12];
    const float* W12w = (const float*)d_in[13]; const float* W12b = (const float*)d_in[14];
    const float* W13w = (const float*)d_in[15]; const float* W13b = (const float*)d_in[16];
    const float* Winw = (const float*)d_in[17]; const float* Winb = (const float*)d_in[18];
    const float* Woutw= (const float*)d_in[19]; const float* Woutb= (const float*)d_in[20];
    const float* n1s  = (const float*)d_in[21]; const float* n1b  = (const float*)d_in[22];
    const float* n2s  = (const float*)d_in[23]; const float* n2b  = (const float*)d_in[24];
    const float* n3s  = (const float*)d_in[25]; const float* n3b  = (const float*)d_in[26];

    float* outY = (float*)d_out;
    float* outE = outY + (size_t)NROW * H_;
    float* dh   = (float*)d_ws;            // B*M*H = 32768 floats = 128 KB

    const int nblk = NROW / TR;            // 12288

    k_zero <<<(B_*M_*H_ + 255)/256, 256, 0, stream>>>(dh);
    k_msg1 <<<nblk, 256, 0, stream>>>(hY, hE, hV, nn, W1w, W1b, W2w, W2b, W3w, W3b, dh);
    k_scale<<<(B_*M_*H_ + 255)/256, 256, 0, stream>>>(dh, Ys);
    k_hy   <<<nblk, 256, 0, stream>>>(hY, dh, nn, Winw, Winb, Woutw, Woutb,
                                      n1s, n1b, n2s, n2b, outY);
    k_he   <<<nblk, 256, 0, stream>>>(outY, hE, hV, W11w, W11b, W12w, W12b, W13w, W13b,
                                      n3s, n3b, outE);
}

// Round 2
// 605.465 us; speedup vs baseline: 10.0255x; 10.0255x over previous
//
#include <hip/hip_runtime.h>
#include <hip/hip_bf16.h>
#include <math.h>

#define H_   128
#define B_   4
#define L_   2048
#define KN   24
#define M_   64
#define FF_  512
#define NROW (B_*L_*KN)   // 196608
#define LKR  (L_*KN)      // 49152
#define RWS  32           // rows per block in MFMA kernels

typedef float f32x4 __attribute__((ext_vector_type(4)));
typedef short s16x8 __attribute__((ext_vector_type(8)));

#define MFMA16(a,b,c) __builtin_amdgcn_mfma_f32_16x16x32_bf16((a),(b),(c),0,0,0)

__device__ __forceinline__ short f2bf(float x){
    union { __hip_bfloat16 h; short s; } u; u.h = __float2bfloat16(x); return u.s;
}
__device__ __forceinline__ float bf2f(short s){
    union { short s; __hip_bfloat16 h; } u; u.s = s; return __bfloat162float(u.h);
}
__device__ __forceinline__ float gelu_f(float x){
    return 0.5f * x * (1.0f + erff(x * 0.70710678118654752f));
}
__device__ __forceinline__ float wsum(float v){
#pragma unroll
    for (int m = 32; m; m >>= 1) v += __shfl_xor(v, m, 64);
    return v;
}
__device__ __forceinline__ s16x8 cvt8(float4 p0, float4 p1){
    s16x8 v;
    v[0]=f2bf(p0.x); v[1]=f2bf(p0.y); v[2]=f2bf(p0.z); v[3]=f2bf(p0.w);
    v[4]=f2bf(p1.x); v[5]=f2bf(p1.y); v[6]=f2bf(p1.z); v[7]=f2bf(p1.w);
    return v;
}

// ---- generic K-loop: A from swizzled bf16 LDS, B from fragment-packed global ----
// A-frag: lane l -> X[rb+(l&15)][ks*32 + (l>>4)*8 + j]   (16B at swizzled block)
// B-frag: packed[tile_n][tile_k][lane][j] (1KB/tile, coalesced load)
template<int KW, int NT>
__device__ __forceinline__ void mm_tiles(const short* xs, int rb,
                                         const short* __restrict__ Wp, int ct0,
                                         int lane, f32x4 (&acc)[NT])
{
    const int r  = rb + (lane & 15);
    const int sw = r & 7;
    const short* xrow = xs + r * KW;
    const s16x8* W8 = (const s16x8*)Wp;
#pragma unroll
    for (int ks = 0; ks < KW/32; ++ks){
        const int blk = (ks << 2) + (lane >> 4);
        s16x8 a = *(const s16x8*)(xrow + ((blk ^ sw) << 3));
#pragma unroll
        for (int t = 0; t < NT; ++t){
            s16x8 b = W8[((ct0 + t)*(KW/32) + ks)*64 + lane];
            acc[t] = MFMA16(a, b, acc[t]);
        }
    }
}

// ---- weight pack: fp32 [N][K] -> bf16 fragment-packed ----
struct PackArgs {
    const float* src[8];
    int K[8];
    int off[8];   // element offsets into dst, ascending
};
#define PACK_TOTAL 294912
__global__ void k_pack(PackArgs pa, short* __restrict__ dst){
    const int gid = blockIdx.x*256 + threadIdx.x;
    if (gid >= PACK_TOTAL) return;
    int w = 0;
#pragma unroll
    for (int i = 1; i < 8; ++i) if (gid >= pa.off[i]) w = i;
    const int e = gid - pa.off[w];
    const int K = pa.K[w];
    const int j = e & 7, lane = (e >> 3) & 63, tt = e >> 9;
    const int kt = K >> 5;
    const int tk = tt % kt, tn = tt / kt;
    const int row = tn*16 + (lane & 15);
    const int col = tk*32 + ((lane >> 4) << 3) + j;
    dst[gid] = f2bf(pa.src[w][(size_t)row*K + col]);
}

__global__ void k_zero(float* __restrict__ dh){
    const int i = blockIdx.x*256 + threadIdx.x;
    if (i < B_*M_*H_) dh[i] = 0.0f;
}
__global__ void k_scale(float* __restrict__ dh, const float* __restrict__ Ys){
    const int i = blockIdx.x*256 + threadIdx.x;
    if (i < B_*M_*H_) dh[i] = dh[i] / Ys[i >> 7];
}

// ---- msg = W3(gelu(W2(gelu(W1([hY|hE|hV]))))), scatter-add into dh ----
__global__ __launch_bounds__(256) void k_msg(
    const float* __restrict__ hY, const float* __restrict__ hE, const float* __restrict__ hV,
    const int* __restrict__ nn,
    const short* __restrict__ W1p, const float* __restrict__ B1,
    const short* __restrict__ W2p, const float* __restrict__ B2,
    const short* __restrict__ W3p, const float* __restrict__ B3,
    float* __restrict__ dh)
{
    __shared__ short xs[RWS*384];
    __shared__ float tf[RWS*128];
    __shared__ short tb[RWS*128];
    const int tid = threadIdx.x, lane = tid & 63, w = tid >> 6;
    const int wr = w >> 1, wc = w & 1, rb = wr*16, cb = wc*64, ct0 = wc*4;
    const int row0 = blockIdx.x * RWS, b = row0 / LKR;
    const int cl = lane & 15, rq = lane >> 4;

    for (int c = tid; c < RWS*48; c += 256){
        const int rr = c/48, k = (c%48) << 3, g = row0 + rr;
        const float* s = (k < 128) ? hY + (size_t)g*128 + k
                      : (k < 256) ? hE + (size_t)g*128 + (k-128)
                                  : hV + (size_t)(g/KN)*128 + (k-256);
        float4 p0 = ((const float4*)s)[0], p1 = ((const float4*)s)[1];
        *(s16x8*)(xs + rr*384 + ((((k>>3) ^ (rr&7))) << 3)) = cvt8(p0, p1);
    }
    __syncthreads();

    f32x4 acc[4];
#pragma unroll
    for (int t = 0; t < 4; ++t){ float bv = B1[cb + t*16 + cl]; acc[t] = (f32x4){bv,bv,bv,bv}; }
    mm_tiles<384,4>(xs, rb, W1p, ct0, lane, acc);
#pragma unroll
    for (int t = 0; t < 4; ++t)
#pragma unroll
        for (int j = 0; j < 4; ++j)
            tf[(rb + rq*4 + j)*128 + cb + t*16 + cl] = gelu_f(acc[t][j]);
    __syncthreads();
    for (int c = tid; c < RWS*16; c += 256){
        const int rr = c >> 4, k = (c & 15) << 3;
        float4 p0 = *(const float4*)(tf + rr*128 + k);
        float4 p1 = *(const float4*)(tf + rr*128 + k + 4);
        *(s16x8*)(tb + rr*128 + ((((k>>3) ^ (rr&7))) << 3)) = cvt8(p0, p1);
    }
    __syncthreads();

#pragma unroll
    for (int t = 0; t < 4; ++t){ float bv = B2[cb + t*16 + cl]; acc[t] = (f32x4){bv,bv,bv,bv}; }
    mm_tiles<128,4>(tb, rb, W2p, ct0, lane, acc);
#pragma unroll
    for (int t = 0; t < 4; ++t)
#pragma unroll
        for (int j = 0; j < 4; ++j)
            tf[(rb + rq*4 + j)*128 + cb + t*16 + cl] = gelu_f(acc[t][j]);
    __syncthreads();
    for (int c = tid; c < RWS*16; c += 256){
        const int rr = c >> 4, k = (c & 15) << 3;
        float4 p0 = *(const float4*)(tf + rr*128 + k);
        float4 p1 = *(const float4*)(tf + rr*128 + k + 4);
        *(s16x8*)(tb + rr*128 + ((((k>>3) ^ (rr&7))) << 3)) = cvt8(p0, p1);
    }
    __syncthreads();

#pragma unroll
    for (int t = 0; t < 4; ++t){ float bv = B3[cb + t*16 + cl]; acc[t] = (f32x4){bv,bv,bv,bv}; }
    mm_tiles<128,4>(tb, rb, W3p, ct0, lane, acc);

    int mj[4];
#pragma unroll
    for (int j = 0; j < 4; ++j) mj[j] = nn[row0 + rb + rq*4 + j];
#pragma unroll
    for (int t = 0; t < 4; ++t){
        const int c = cb + t*16 + cl;
#pragma unroll
        for (int j = 0; j < 4; ++j)
            __hip_atomic_fetch_add(dh + ((size_t)(b*M_ + mj[j]))*H_ + c, acc[t][j],
                                   __ATOMIC_RELAXED, __HIP_MEMORY_SCOPE_AGENT);
    }
}

// ---- h_Y = LN2( y1 + Wout(gelu(Win(y1))) ), y1 = LN1(hY + dh[b,nn]) ----
__global__ __launch_bounds__(256) void k_hy(
    const float* __restrict__ hY, const float* __restrict__ dhs, const int* __restrict__ nn,
    const short* __restrict__ Winp, const float* __restrict__ Bin,
    const short* __restrict__ Woutp, const float* __restrict__ Bout,
    const float* __restrict__ n1s, const float* __restrict__ n1b,
    const float* __restrict__ n2s, const float* __restrict__ n2b,
    float* __restrict__ outY)
{
    __shared__ short xb[RWS*128];
    __shared__ short ffb[RWS*512];
    __shared__ float tf[RWS*128];
    const int tid = threadIdx.x, lane = tid & 63, w = tid >> 6;
    const int wr = w >> 1, wc = w & 1, rb = wr*16, cb = wc*64;
    const int row0 = blockIdx.x * RWS, b = row0 / LKR;
    const int cl = lane & 15, rq = lane >> 4;

    for (int c = tid; c < RWS*16; c += 256){
        const int rr = c >> 4, k = (c & 15) << 3, g = row0 + rr;
        const int m = nn[g];
        const float* a = hY + (size_t)g*128 + k;
        const float* d = dhs + ((size_t)(b*M_ + m))*128 + k;
        float4 a0 = ((const float4*)a)[0], a1 = ((const float4*)a)[1];
        float4 d0 = ((const float4*)d)[0], d1 = ((const float4*)d)[1];
        float4 r0, r1;
        r0.x=a0.x+d0.x; r0.y=a0.y+d0.y; r0.z=a0.z+d0.z; r0.w=a0.w+d0.w;
        r1.x=a1.x+d1.x; r1.y=a1.y+d1.y; r1.z=a1.z+d1.z; r1.w=a1.w+d1.w;
        *(float4*)(tf + rr*128 + k)     = r0;
        *(float4*)(tf + rr*128 + k + 4) = r1;
    }
    __syncthreads();

#pragma unroll
    for (int i = 0; i < 8; ++i){   // LN1 -> xb (bf16, swizzled)
        const int r = w*8 + i;
        const float v0 = tf[r*128 + lane], v1 = tf[r*128 + lane + 64];
        const float mu = wsum(v0 + v1) * (1.0f/128.0f);
        const float d0 = v0 - mu, d1 = v1 - mu;
        const float var = wsum(d0*d0 + d1*d1) * (1.0f/128.0f);
        const float rs = rsqrtf(var + 1e-5f);
        const float y0 = d0*rs*n1s[lane]      + n1b[lane];
        const float y1 = d1*rs*n1s[lane + 64] + n1b[lane + 64];
        const int c0 = lane, c1 = lane + 64;
        xb[r*128 + (((c0>>3) ^ (r&7)) << 3) + (c0&7)] = f2bf(y0);
        xb[r*128 + (((c1>>3) ^ (r&7)) << 3) + (c1&7)] = f2bf(y1);
    }
    __syncthreads();

    for (int p = 0; p < 4; ++p){   // Win in 4 column passes of 128
        f32x4 acc[4];
        const int ct0 = p*8 + wc*4;
#pragma unroll
        for (int t = 0; t < 4; ++t){ float bv = Bin[p*128 + cb + t*16 + cl]; acc[t] = (f32x4){bv,bv,bv,bv}; }
        mm_tiles<128,4>(xb, rb, Winp, ct0, lane, acc);
#pragma unroll
        for (int t = 0; t < 4; ++t)
#pragma unroll
            for (int j = 0; j < 4; ++j)
                tf[(rb + rq*4 + j)*128 + cb + t*16 + cl] = gelu_f(acc[t][j]);
        __syncthreads();
        for (int c = tid; c < RWS*16; c += 256){
            const int rr = c >> 4, k = (c & 15) << 3, kg = p*128 + k;
            float4 p0 = *(const float4*)(tf + rr*128 + k);
            float4 p1 = *(const float4*)(tf + rr*128 + k + 4);
            *(s16x8*)(ffb + rr*512 + ((((kg>>3) ^ (rr&7))) << 3)) = cvt8(p0, p1);
        }
        __syncthreads();
    }

    f32x4 acc[4];
#pragma unroll
    for (int t = 0; t < 4; ++t){ float bv = Bout[cb + t*16 + cl]; acc[t] = (f32x4){bv,bv,bv,bv}; }
    mm_tiles<512,4>(ffb, rb, Woutp, wc*4, lane, acc);
#pragma unroll
    for (int t = 0; t < 4; ++t)
#pragma unroll
        for (int j = 0; j < 4; ++j)
            tf[(rb + rq*4 + j)*128 + cb + t*16 + cl] = acc[t][j];
    __syncthreads();

#pragma unroll
    for (int i = 0; i < 8; ++i){   // LN2 with residual from xb -> outY
        const int r = w*8 + i, g = row0 + r;
        const int c0 = lane, c1 = lane + 64;
        const float x0 = bf2f(xb[r*128 + (((c0>>3) ^ (r&7)) << 3) + (c0&7)]);
        const float x1 = bf2f(xb[r*128 + (((c1>>3) ^ (r&7)) << 3) + (c1&7)]);
        const float v0 = tf[r*128 + lane] + x0, v1 = tf[r*128 + lane + 64] + x1;
        const float mu = wsum(v0 + v1) * (1.0f/128.0f);
        const float d0 = v0 - mu, d1 = v1 - mu;
        const float var = wsum(d0*d0 + d1*d1) * (1.0f/128.0f);
        const float rs = rsqrtf(var + 1e-5f);
        outY[(size_t)g*128 + lane]      = d0*rs*n2s[lane]    + n2b[lane];
        outY[(size_t)g*128 + lane + 64] = d1*rs*n2s[lane+64] + n2b[lane+64];
    }
}

// ---- h_E = LN3( hE + W13(gelu(W12(gelu(W11([h_Y|hE|hV]))))) ) ----
__global__ __launch_bounds__(256) void k_he(
    const float* __restrict__ hYn, const float* __restrict__ hE, const float* __restrict__ hV,
    const short* __restrict__ W1p, const float* __restrict__ B1,
    const short* __restrict__ W2p, const float* __restrict__ B2,
    const short* __restrict__ W3p, const float* __restrict__ B3,
    const float* __restrict__ n3s, const float* __restrict__ n3b,
    float* __restrict__ outE)
{
    __shared__ short xs[RWS*384];
    __shared__ float tf[RWS*128];
    __shared__ short tb[RWS*128];
    const int tid = threadIdx.x, lane = tid & 63, w = tid >> 6;
    const int wr = w >> 1, wc = w & 1, rb = wr*16, cb = wc*64, ct0 = wc*4;
    const int row0 = blockIdx.x * RWS;
    const int cl = lane & 15, rq = lane >> 4;

    for (int c = tid; c < RWS*48; c += 256){
        const int rr = c/48, k = (c%48) << 3, g = row0 + rr;
        const float* s = (k < 128) ? hYn + (size_t)g*128 + k
                      : (k < 256) ? hE  + (size_t)g*128 + (k-128)
                                  : hV  + (size_t)(g/KN)*128 + (k-256);
        float4 p0 = ((const float4*)s)[0], p1 = ((const float4*)s)[1];
        *(s16x8*)(xs + rr*384 + ((((k>>3) ^ (rr&7))) << 3)) = cvt8(p0, p1);
    }
    __syncthreads();

    f32x4 acc[4];
#pragma unroll
    for (int t = 0; t < 4; ++t){ float bv = B1[cb + t*16 + cl]; acc[t] = (f32x4){bv,bv,bv,bv}; }
    mm_tiles<384,4>(xs, rb, W1p, ct0, lane, acc);
#pragma unroll
    for (int t = 0; t < 4; ++t)
#pragma unroll
        for (int j = 0; j < 4; ++j)
            tf[(rb + rq*4 + j)*128 + cb + t*16 + cl] = gelu_f(acc[t][j]);
    __syncthreads();
    for (int c = tid; c < RWS*16; c += 256){
        const int rr = c >> 4, k = (c & 15) << 3;
        float4 p0 = *(const float4*)(tf + rr*128 + k);
        float4 p1 = *(const float4*)(tf + rr*128 + k + 4);
        *(s16x8*)(tb + rr*128 + ((((k>>3) ^ (rr&7))) << 3)) = cvt8(p0, p1);
    }
    __syncthreads();

#pragma unroll
    for (int t = 0; t < 4; ++t){ float bv = B2[cb + t*16 + cl]; acc[t] = (f32x4){bv,bv,bv,bv}; }
    mm_tiles<128,4>(tb, rb, W2p, ct0, lane, acc);
#pragma unroll
    for (int t = 0; t < 4; ++t)
#pragma unroll
        for (int j = 0; j < 4; ++j)
            tf[(rb + rq*4 + j)*128 + cb + t*16 + cl] = gelu_f(acc[t][j]);
    __syncthreads();
    for (int c = tid; c < RWS*16; c += 256){
        const int rr = c >> 4, k = (c & 15) << 3;
        float4 p0 = *(const float4*)(tf + rr*128 + k);
        float4 p1 = *(const float4*)(tf + rr*128 + k + 4);
        *(s16x8*)(tb + rr*128 + ((((k>>3) ^ (rr&7))) << 3)) = cvt8(p0, p1);
    }
    __syncthreads();

#pragma unroll
    for (int t = 0; t < 4; ++t){ float bv = B3[cb + t*16 + cl]; acc[t] = (f32x4){bv,bv,bv,bv}; }
    mm_tiles<128,4>(tb, rb, W3p, ct0, lane, acc);
#pragma unroll
    for (int t = 0; t < 4; ++t)
#pragma unroll
        for (int j = 0; j < 4; ++j)
            tf[(rb + rq*4 + j)*128 + cb + t*16 + cl] = acc[t][j];
    __syncthreads();

#pragma unroll
    for (int i = 0; i < 8; ++i){   // residual + LN3 -> outE
        const int r = w*8 + i, g = row0 + r;
        const float v0 = tf[r*128 + lane]      + hE[(size_t)g*128 + lane];
        const float v1 = tf[r*128 + lane + 64] + hE[(size_t)g*128 + lane + 64];
        const float mu = wsum(v0 + v1) * (1.0f/128.0f);
        const float d0 = v0 - mu, d1 = v1 - mu;
        const float var = wsum(d0*d0 + d1*d1) * (1.0f/128.0f);
        const float rs = rsqrtf(var + 1e-5f);
        outE[(size_t)g*128 + lane]      = d0*rs*n3s[lane]    + n3b[lane];
        outE[(size_t)g*128 + lane + 64] = d1*rs*n3s[lane+64] + n3b[lane+64];
    }
}

extern "C" void kernel_launch(void* const* d_in, const int* in_sizes, int n_in,
                              void* d_out, int out_size, void* d_ws, size_t ws_size,
                              hipStream_t stream) {
    const int*   nn   = (const int*)  d_in[0];
    const float* Ys   = (const float*)d_in[1];
    const float* hY   = (const float*)d_in[2];
    const float* hE   = (const float*)d_in[3];
    const float* hV   = (const float*)d_in[4];
    const float* W1w  = (const float*)d_in[5];  const float* W1b  = (const float*)d_in[6];
    const float* W2w  = (const float*)d_in[7];  const float* W2b  = (const float*)d_in[8];
    const float* W3w  = (const float*)d_in[9];  const float* W3b  = (const float*)d_in[10];
    const float* W11w = (const float*)d_in[11]; const float* W11b = (const float*)d_in[12];
    const float* W12w = (const float*)d_in[13]; const float* W12b = (const float*)d_in[14];
    const float* W13w = (const float*)d_in[15]; const float* W13b = (const float*)d_in[16];
    const float* Winw = (const float*)d_in[17]; const float* Winb = (const float*)d_in[18];
    const float* Woutw= (const float*)d_in[19]; const float* Woutb= (const float*)d_in[20];
    const float* n1s  = (const float*)d_in[21]; const float* n1b  = (const float*)d_in[22];
    const float* n2s  = (const float*)d_in[23]; const float* n2b  = (const float*)d_in[24];
    const float* n3s  = (const float*)d_in[25]; const float* n3b  = (const float*)d_in[26];

    float* outY = (float*)d_out;
    float* outE = outY + (size_t)NROW * H_;

    float* dh = (float*)d_ws;                        // 128 KB
    short* wp = (short*)((char*)d_ws + 131072);      // packed bf16 weights

    // packed offsets (elements)
    const int oW1 = 0,      oW2 = 49152,  oW3 = 65536,  oW11 = 81920;
    const int oW12 = 131072, oW13 = 147456, oWin = 163840, oWout = 229376;

    PackArgs pa;
    pa.src[0]=W1w;  pa.K[0]=384; pa.off[0]=oW1;
    pa.src[1]=W2w;  pa.K[1]=128; pa.off[1]=oW2;
    pa.src[2]=W3w;  pa.K[2]=128; pa.off[2]=oW3;
    pa.src[3]=W11w; pa.K[3]=384; pa.off[3]=oW11;
    pa.src[4]=W12w; pa.K[4]=128; pa.off[4]=oW12;
    pa.src[5]=W13w; pa.K[5]=128; pa.off[5]=oW13;
    pa.src[6]=Winw; pa.K[6]=128; pa.off[6]=oWin;
    pa.src[7]=Woutw;pa.K[7]=512; pa.off[7]=oWout;

    const int nblk = NROW / RWS;   // 6144

    k_pack <<<(PACK_TOTAL + 255)/256, 256, 0, stream>>>(pa, wp);
    k_zero <<<(B_*M_*H_ + 255)/256, 256, 0, stream>>>(dh);
    k_msg  <<<nblk, 256, 0, stream>>>(hY, hE, hV, nn,
                                      wp + oW1, W1b, wp + oW2, W2b, wp + oW3, W3b, dh);
    k_scale<<<(B_*M_*H_ + 255)/256, 256, 0, stream>>>(dh, Ys);
    k_hy   <<<nblk, 256, 0, stream>>>(hY, dh, nn, wp + oWin, Winb, wp + oWout, Woutb,
                                      n1s, n1b, n2s, n2b, outY);
    k_he   <<<nblk, 256, 0, stream>>>(outY, hE, hV,
                                      wp + oW11, W11b, wp + oW12, W12b, wp + oW13, W13b,
                                      n3s, n3b, outE);
}

// Round 3
// 395.292 us; speedup vs baseline: 15.3560x; 1.5317x over previous
//
#include <hip/hip_runtime.h>
#include <hip/hip_bf16.h>

#define H_   128
#define B_   4
#define L_   2048
#define KN   24
#define M_   64
#define NROW (B_*L_*KN)   // 196608
#define LKR  (L_*KN)      // 49152

typedef float f32x4 __attribute__((ext_vector_type(4)));
typedef short s16x8 __attribute__((ext_vector_type(8)));

#define MFMA16(a,b,c) __builtin_amdgcn_mfma_f32_16x16x32_bf16((a),(b),(c),0,0,0)

static __device__ __forceinline__ unsigned short f2bfu(float x){
    union { __hip_bfloat16 h; unsigned short s; } u; u.h = __float2bfloat16(x); return u.s;
}
static __device__ __forceinline__ float bf2f(unsigned short s){
    union { unsigned short s; __hip_bfloat16 h; } u; u.s = s; return __bfloat162float(u.h);
}
static __device__ __forceinline__ unsigned packbf(float lo, float hi){
    return (unsigned)f2bfu(lo) | ((unsigned)f2bfu(hi) << 16);
}
// tanh-form gelu: x * sigmoid(1.59577*(x + 0.044715 x^3)); |err| <= ~3e-3
static __device__ __forceinline__ float gelu_f(float x){
    const float x2 = x*x;
    const float u  = x * fmaf(x2, -0.10294265f, -2.3022083f);  // -log2(e)*(c1 + c3 x^2)
    const float e  = __builtin_amdgcn_exp2f(u);
    return x * __builtin_amdgcn_rcpf(1.0f + e);
}
static __device__ __forceinline__ float wsum(float v){
#pragma unroll
    for (int m = 32; m; m >>= 1) v += __shfl_xor(v, m, 64);
    return v;
}
static __device__ __forceinline__ s16x8 cvt8(float4 p0, float4 p1){
    s16x8 v;
    v[0]=(short)f2bfu(p0.x); v[1]=(short)f2bfu(p0.y); v[2]=(short)f2bfu(p0.z); v[3]=(short)f2bfu(p0.w);
    v[4]=(short)f2bfu(p1.x); v[5]=(short)f2bfu(p1.y); v[6]=(short)f2bfu(p1.z); v[7]=(short)f2bfu(p1.w);
    return v;
}
// bf16 LDS, 16B-block XOR swizzle: element [r][c] at r*KW + ((c>>3 ^ (r&7))<<3) + (c&7)
template<int KW>
static __device__ __forceinline__ s16x8 afrag(const short* xs, int r, int blk){
    return *(const s16x8*)(xs + r*KW + ((blk ^ (r & 7)) << 3));
}
template<int KW>
static __device__ __forceinline__ void bstore(short* xs, int r, int c, unsigned v){
    *(unsigned*)(xs + r*KW + ((((c >> 3) ^ (r & 7))) << 3) + (c & 7)) = v;
}
// fp32 LDS, 16B-block XOR swizzle (KW=128)
static __device__ __forceinline__ int fidx(int r, int c){
    return r*128 + ((((c >> 2) ^ (r & 7))) << 2) + (c & 3);
}

// swapped: D = (W in A-role) x (act in B-role)  ->  lane: actrow=cl, feat=(rq*4+j)
template<int KWACT, int NKS>
static __device__ __forceinline__ void mm_sw(const short* act, const short* __restrict__ Wp,
    int ktS, int kt0, int tn0, int lane, f32x4 (&acc)[2][2])
{
    const int cl = lane & 15, rq = lane >> 4;
    const s16x8* W8 = (const s16x8*)Wp;
#pragma unroll
    for (int ks = 0; ks < NKS; ++ks){
        const int blk = (ks << 2) + rq;
        const s16x8 a0 = afrag<KWACT>(act, cl, blk);
        const s16x8 a1 = afrag<KWACT>(act, 16 + cl, blk);
#pragma unroll
        for (int t = 0; t < 2; ++t){
            const s16x8 wf = W8[(size_t)((tn0 + t)*ktS + kt0 + ks)*64 + lane];
            acc[0][t] = MFMA16(wf, a0, acc[0][t]);
            acc[1][t] = MFMA16(wf, a1, acc[1][t]);
        }
    }
}
// natural: D = (act in A-role) x (W in B-role) -> lane: feat=cl, actrow=(rq*4+j)
template<int KWACT, int NKS>
static __device__ __forceinline__ void mm_nat(const short* act, const short* __restrict__ Wp,
    int ktS, int kt0, int tn0, int lane, f32x4 (&acc)[2][2])
{
    const int cl = lane & 15, rq = lane >> 4;
    const s16x8* W8 = (const s16x8*)Wp;
#pragma unroll
    for (int ks = 0; ks < NKS; ++ks){
        const int blk = (ks << 2) + rq;
        const s16x8 a0 = afrag<KWACT>(act, cl, blk);
        const s16x8 a1 = afrag<KWACT>(act, 16 + cl, blk);
#pragma unroll
        for (int t = 0; t < 2; ++t){
            const s16x8 wf = W8[(size_t)((tn0 + t)*ktS + kt0 + ks)*64 + lane];
            acc[0][t] = MFMA16(a0, wf, acc[0][t]);
            acc[1][t] = MFMA16(a1, wf, acc[1][t]);
        }
    }
}

// ---- weight pack: fp32 [N][K] -> bf16 fragment-packed (unchanged layout) ----
struct PackArgs {
    const float* src[8];
    int K[8];
    int off[8];
};
#define PACK_TOTAL 294912
__global__ void k_pack(PackArgs pa, short* __restrict__ dst){
    const int gid = blockIdx.x*256 + threadIdx.x;
    if (gid >= PACK_TOTAL) return;
    int w = 0;
#pragma unroll
    for (int i = 1; i < 8; ++i) if (gid >= pa.off[i]) w = i;
    const int e = gid - pa.off[w];
    const int K = pa.K[w];
    const int j = e & 7, lane = (e >> 3) & 63, tt = e >> 9;
    const int kt = K >> 5;
    const int tk = tt % kt, tn = tt / kt;
    const int row = tn*16 + (lane & 15);
    const int col = tk*32 + ((lane >> 4) << 3) + j;
    dst[gid] = (short)f2bfu(pa.src[w][(size_t)row*K + col]);
}

__global__ void k_zero(float* __restrict__ dh){
    const int i = blockIdx.x*256 + threadIdx.x;
    if (i < B_*M_*H_) dh[i] = 0.0f;
}
__global__ void k_scale(float* __restrict__ dh, const float* __restrict__ Ys){
    const int i = blockIdx.x*256 + threadIdx.x;
    if (i < B_*M_*H_) dh[i] = dh[i] / Ys[i >> 7];
}

// ---- msg = W3(gelu(W2(gelu(W1([hY|hE|hV]))))), scatter-add into dh ----
__global__ __launch_bounds__(256) void k_msg(
    const float* __restrict__ hY, const float* __restrict__ hE, const float* __restrict__ hV,
    const int* __restrict__ nn,
    const short* __restrict__ W1p, const float* __restrict__ B1,
    const short* __restrict__ W2p, const float* __restrict__ B2,
    const short* __restrict__ W3p, const float* __restrict__ B3,
    float* __restrict__ dh)
{
    __shared__ short xs[32*384];    // 24K
    __shared__ short tb1[32*128];   // 8K
    __shared__ short tb2[32*128];   // 8K
    const int tid = threadIdx.x, lane = tid & 63, w = tid >> 6;
    const int cl = lane & 15, rq = lane >> 4;
    const int row0 = blockIdx.x * 32, b = row0 / LKR;
    const int tn0 = 2*w;

    for (int c = tid; c < 32*48; c += 256){
        const int rr = c/48, k = (c - rr*48) << 3, g = row0 + rr;
        const float* s = (k < 128) ? hY + (size_t)g*128 + k
                      : (k < 256) ? hE + (size_t)g*128 + (k-128)
                                  : hV + (size_t)(g/KN)*128 + (k-256);
        float4 p0 = ((const float4*)s)[0], p1 = ((const float4*)s)[1];
        *(s16x8*)(xs + rr*384 + ((((k>>3) ^ (rr&7))) << 3)) = cvt8(p0, p1);
    }
    __syncthreads();

    f32x4 acc[2][2];
#pragma unroll
    for (int t = 0; t < 2; ++t)
#pragma unroll
        for (int j = 0; j < 4; ++j){
            const float bv = B1[(tn0+t)*16 + rq*4 + j];
            acc[0][t][j] = bv; acc[1][t][j] = bv;
        }
    mm_sw<384,12>(xs, W1p, 12, 0, tn0, lane, acc);
#pragma unroll
    for (int rt = 0; rt < 2; ++rt)
#pragma unroll
        for (int t = 0; t < 2; ++t){
            const int r = rt*16 + cl, cb = (tn0+t)*16 + rq*4;
            bstore<128>(tb1, r, cb,   packbf(gelu_f(acc[rt][t][0]), gelu_f(acc[rt][t][1])));
            bstore<128>(tb1, r, cb+2, packbf(gelu_f(acc[rt][t][2]), gelu_f(acc[rt][t][3])));
        }
    __syncthreads();

#pragma unroll
    for (int t = 0; t < 2; ++t)
#pragma unroll
        for (int j = 0; j < 4; ++j){
            const float bv = B2[(tn0+t)*16 + rq*4 + j];
            acc[0][t][j] = bv; acc[1][t][j] = bv;
        }
    mm_sw<128,4>(tb1, W2p, 4, 0, tn0, lane, acc);
#pragma unroll
    for (int rt = 0; rt < 2; ++rt)
#pragma unroll
        for (int t = 0; t < 2; ++t){
            const int r = rt*16 + cl, cb = (tn0+t)*16 + rq*4;
            bstore<128>(tb2, r, cb,   packbf(gelu_f(acc[rt][t][0]), gelu_f(acc[rt][t][1])));
            bstore<128>(tb2, r, cb+2, packbf(gelu_f(acc[rt][t][2]), gelu_f(acc[rt][t][3])));
        }
    __syncthreads();

    f32x4 a3[2][2];
#pragma unroll
    for (int t = 0; t < 2; ++t){
        const float bv = B3[(tn0+t)*16 + cl];
        a3[0][t] = (f32x4){bv,bv,bv,bv};
        a3[1][t] = (f32x4){bv,bv,bv,bv};
    }
    mm_nat<128,4>(tb2, W3p, 4, 0, tn0, lane, a3);

#pragma unroll
    for (int rt = 0; rt < 2; ++rt){
        int mj[4];
#pragma unroll
        for (int j = 0; j < 4; ++j) mj[j] = nn[row0 + rt*16 + rq*4 + j];
#pragma unroll
        for (int t = 0; t < 2; ++t){
            const int c = (tn0+t)*16 + cl;
#pragma unroll
            for (int j = 0; j < 4; ++j)
                __hip_atomic_fetch_add(dh + ((size_t)(b*M_ + mj[j]))*128 + c, a3[rt][t][j],
                                       __ATOMIC_RELAXED, __HIP_MEMORY_SCOPE_AGENT);
        }
    }
}

// ---- h_Y = LN2( y1 + Wout(gelu(Win(y1))) ), y1 = LN1(hY + dh[b,nn]) ----
__global__ __launch_bounds__(256) void k_hy(
    const float* __restrict__ hY, const float* __restrict__ dhs, const int* __restrict__ nn,
    const short* __restrict__ Winp, const float* __restrict__ Bin,
    const short* __restrict__ Woutp, const float* __restrict__ Bout,
    const float* __restrict__ n1s, const float* __restrict__ n1b,
    const float* __restrict__ n2s, const float* __restrict__ n2b,
    float* __restrict__ outY)
{
    __shared__ float tf[32*128];    // 16K
    __shared__ short xb[32*128];    // 8K
    __shared__ short ffc[32*128];   // 8K
    const int tid = threadIdx.x, lane = tid & 63, w = tid >> 6;
    const int cl = lane & 15, rq = lane >> 4;
    const int row0 = blockIdx.x * 32, b = row0 / LKR;

    for (int c = tid; c < 32*16; c += 256){
        const int rr = c >> 4, k = (c & 15) << 3, g = row0 + rr;
        const int m = nn[g];
        const float* a = hY  + (size_t)g*128 + k;
        const float* d = dhs + ((size_t)(b*M_ + m))*128 + k;
        float4 a0 = ((const float4*)a)[0], a1 = ((const float4*)a)[1];
        float4 d0 = ((const float4*)d)[0], d1 = ((const float4*)d)[1];
        float4 r0 = {a0.x+d0.x, a0.y+d0.y, a0.z+d0.z, a0.w+d0.w};
        float4 r1 = {a1.x+d1.x, a1.y+d1.y, a1.z+d1.z, a1.w+d1.w};
        const int s = rr & 7, kb = k >> 2;
        *(float4*)&tf[rr*128 + ((kb ^ s) << 2)]     = r0;
        *(float4*)&tf[rr*128 + (((kb+1) ^ s) << 2)] = r1;
    }
    __syncthreads();

#pragma unroll
    for (int i = 0; i < 8; ++i){   // LN1 -> xb (bf16, swizzled)
        const int r = w*8 + i;
        const float v0 = tf[fidx(r, lane)], v1 = tf[fidx(r, lane+64)];
        const float mu = wsum(v0+v1) * (1.0f/128.0f);
        const float d0 = v0-mu, d1 = v1-mu;
        const float var = wsum(d0*d0 + d1*d1) * (1.0f/128.0f);
        const float rs = rsqrtf(var + 1e-5f);
        const float y0 = d0*rs*n1s[lane]    + n1b[lane];
        const float y1 = d1*rs*n1s[lane+64] + n1b[lane+64];
        const int c1 = lane + 64;
        xb[r*128 + ((((lane>>3) ^ (r&7))) << 3) + (lane&7)] = (short)f2bfu(y0);
        xb[r*128 + ((((c1>>3)   ^ (r&7))) << 3) + (c1&7)]   = (short)f2bfu(y1);
    }
    __syncthreads();

    f32x4 accW[2][2];
#pragma unroll
    for (int t = 0; t < 2; ++t)
#pragma unroll
        for (int j = 0; j < 4; ++j){
            const float bv = Bout[(2*w+t)*16 + rq*4 + j];
            accW[0][t][j] = bv; accW[1][t][j] = bv;
        }

    for (int p = 0; p < 4; ++p){
        f32x4 ai[2][2];
#pragma unroll
        for (int t = 0; t < 2; ++t)
#pragma unroll
            for (int j = 0; j < 4; ++j){
                const float bv = Bin[p*128 + (2*w+t)*16 + rq*4 + j];
                ai[0][t][j] = bv; ai[1][t][j] = bv;
            }
        mm_sw<128,4>(xb, Winp, 4, 0, p*8 + 2*w, lane, ai);
        __syncthreads();            // prior pass's Wout reads of ffc complete
#pragma unroll
        for (int rt = 0; rt < 2; ++rt)
#pragma unroll
            for (int t = 0; t < 2; ++t){
                const int r = rt*16 + cl, cb = (2*w+t)*16 + rq*4;
                bstore<128>(ffc, r, cb,   packbf(gelu_f(ai[rt][t][0]), gelu_f(ai[rt][t][1])));
                bstore<128>(ffc, r, cb+2, packbf(gelu_f(ai[rt][t][2]), gelu_f(ai[rt][t][3])));
            }
        __syncthreads();
        mm_sw<128,4>(ffc, Woutp, 16, p*4, 2*w, lane, accW);
    }

#pragma unroll
    for (int rt = 0; rt < 2; ++rt)
#pragma unroll
        for (int t = 0; t < 2; ++t){
            const int r = rt*16 + cl, cb = (2*w+t)*16 + rq*4;
            float4 o = {accW[rt][t][0], accW[rt][t][1], accW[rt][t][2], accW[rt][t][3]};
            *(float4*)&tf[r*128 + ((((cb>>2) ^ (r&7))) << 2)] = o;
        }
    __syncthreads();

#pragma unroll
    for (int i = 0; i < 8; ++i){   // LN2 with residual from xb -> outY
        const int r = w*8 + i, g = row0 + r;
        const int c1 = lane + 64;
        const float x0 = bf2f((unsigned short)xb[r*128 + ((((lane>>3) ^ (r&7))) << 3) + (lane&7)]);
        const float x1 = bf2f((unsigned short)xb[r*128 + ((((c1>>3)   ^ (r&7))) << 3) + (c1&7)]);
        const float v0 = tf[fidx(r, lane)]    + x0;
        const float v1 = tf[fidx(r, lane+64)] + x1;
        const float mu = wsum(v0+v1) * (1.0f/128.0f);
        const float d0 = v0-mu, d1 = v1-mu;
        const float var = wsum(d0*d0 + d1*d1) * (1.0f/128.0f);
        const float rs = rsqrtf(var + 1e-5f);
        outY[(size_t)g*128 + lane]      = d0*rs*n2s[lane]    + n2b[lane];
        outY[(size_t)g*128 + lane + 64] = d1*rs*n2s[lane+64] + n2b[lane+64];
    }
}

// ---- h_E = LN3( hE + W13(gelu(W12(gelu(W11([h_Y|hE|hV]))))) ) ----
__global__ __launch_bounds__(256) void k_he(
    const float* __restrict__ hYn, const float* __restrict__ hE, const float* __restrict__ hV,
    const short* __restrict__ W1p, const float* __restrict__ B1,
    const short* __restrict__ W2p, const float* __restrict__ B2,
    const short* __restrict__ W3p, const float* __restrict__ B3,
    const float* __restrict__ n3s, const float* __restrict__ n3b,
    float* __restrict__ outE)
{
    __shared__ __align__(16) char pool[40960];
    short* xs  = (short*)pool;            // 24K (W1 stage; dead after W1)
    float* tf  = (float*)pool;            // 16K alias over xs (used after W13)
    short* tb1 = (short*)(pool + 24576);  // 8K
    short* tb2 = (short*)(pool + 32768);  // 8K
    const int tid = threadIdx.x, lane = tid & 63, w = tid >> 6;
    const int cl = lane & 15, rq = lane >> 4;
    const int row0 = blockIdx.x * 32;
    const int tn0 = 2*w;

    for (int c = tid; c < 32*48; c += 256){
        const int rr = c/48, k = (c - rr*48) << 3, g = row0 + rr;
        const float* s = (k < 128) ? hYn + (size_t)g*128 + k
                      : (k < 256) ? hE  + (size_t)g*128 + (k-128)
                                  : hV  + (size_t)(g/KN)*128 + (k-256);
        float4 p0 = ((const float4*)s)[0], p1 = ((const float4*)s)[1];
        *(s16x8*)(xs + rr*384 + ((((k>>3) ^ (rr&7))) << 3)) = cvt8(p0, p1);
    }
    __syncthreads();

    f32x4 acc[2][2];
#pragma unroll
    for (int t = 0; t < 2; ++t)
#pragma unroll
        for (int j = 0; j < 4; ++j){
            const float bv = B1[(tn0+t)*16 + rq*4 + j];
            acc[0][t][j] = bv; acc[1][t][j] = bv;
        }
    mm_sw<384,12>(xs, W1p, 12, 0, tn0, lane, acc);
#pragma unroll
    for (int rt = 0; rt < 2; ++rt)
#pragma unroll
        for (int t = 0; t < 2; ++t){
            const int r = rt*16 + cl, cb = (tn0+t)*16 + rq*4;
            bstore<128>(tb1, r, cb,   packbf(gelu_f(acc[rt][t][0]), gelu_f(acc[rt][t][1])));
            bstore<128>(tb1, r, cb+2, packbf(gelu_f(acc[rt][t][2]), gelu_f(acc[rt][t][3])));
        }
    __syncthreads();

#pragma unroll
    for (int t = 0; t < 2; ++t)
#pragma unroll
        for (int j = 0; j < 4; ++j){
            const float bv = B2[(tn0+t)*16 + rq*4 + j];
            acc[0][t][j] = bv; acc[1][t][j] = bv;
        }
    mm_sw<128,4>(tb1, W2p, 4, 0, tn0, lane, acc);
#pragma unroll
    for (int rt = 0; rt < 2; ++rt)
#pragma unroll
        for (int t = 0; t < 2; ++t){
            const int r = rt*16 + cl, cb = (tn0+t)*16 + rq*4;
            bstore<128>(tb2, r, cb,   packbf(gelu_f(acc[rt][t][0]), gelu_f(acc[rt][t][1])));
            bstore<128>(tb2, r, cb+2, packbf(gelu_f(acc[rt][t][2]), gelu_f(acc[rt][t][3])));
        }
    __syncthreads();

#pragma unroll
    for (int t = 0; t < 2; ++t)
#pragma unroll
        for (int j = 0; j < 4; ++j){
            const float bv = B3[(tn0+t)*16 + rq*4 + j];
            acc[0][t][j] = bv; acc[1][t][j] = bv;
        }
    mm_sw<128,4>(tb2, W3p, 4, 0, tn0, lane, acc);

#pragma unroll
    for (int rt = 0; rt < 2; ++rt)
#pragma unroll
        for (int t = 0; t < 2; ++t){
            const int r = rt*16 + cl, cb = (tn0+t)*16 + rq*4;
            float4 o = {acc[rt][t][0], acc[rt][t][1], acc[rt][t][2], acc[rt][t][3]};
            *(float4*)&tf[r*128 + ((((cb>>2) ^ (r&7))) << 2)] = o;
        }
    __syncthreads();

#pragma unroll
    for (int i = 0; i < 8; ++i){   // residual + LN3 -> outE
        const int r = w*8 + i, g = row0 + r;
        const float v0 = tf[fidx(r, lane)]    + hE[(size_t)g*128 + lane];
        const float v1 = tf[fidx(r, lane+64)] + hE[(size_t)g*128 + lane + 64];
        const float mu = wsum(v0+v1) * (1.0f/128.0f);
        const float d0 = v0-mu, d1 = v1-mu;
        const float var = wsum(d0*d0 + d1*d1) * (1.0f/128.0f);
        const float rs = rsqrtf(var + 1e-5f);
        outE[(size_t)g*128 + lane]      = d0*rs*n3s[lane]    + n3b[lane];
        outE[(size_t)g*128 + lane + 64] = d1*rs*n3s[lane+64] + n3b[lane+64];
    }
}

extern "C" void kernel_launch(void* const* d_in, const int* in_sizes, int n_in,
                              void* d_out, int out_size, void* d_ws, size_t ws_size,
                              hipStream_t stream) {
    const int*   nn   = (const int*)  d_in[0];
    const float* Ys   = (const float*)d_in[1];
    const float* hY   = (const float*)d_in[2];
    const float* hE   = (const float*)d_in[3];
    const float* hV   = (const float*)d_in[4];
    const float* W1w  = (const float*)d_in[5];  const float* W1b  = (const float*)d_in[6];
    const float* W2w  = (const float*)d_in[7];  const float* W2b  = (const float*)d_in[8];
    const float* W3w  = (const float*)d_in[9];  const float* W3b  = (const float*)d_in[10];
    const float* W11w = (const float*)d_in[11]; const float* W11b = (const float*)d_in[12];
    const float* W12w = (const float*)d_in[13]; const float* W12b = (const float*)d_in[14];
    const float* W13w = (const float*)d_in[15]; const float* W13b = (const float*)d_in[16];
    const float* Winw = (const float*)d_in[17]; const float* Winb = (const float*)d_in[18];
    const float* Woutw= (const float*)d_in[19]; const float* Woutb= (const float*)d_in[20];
    const float* n1s  = (const float*)d_in[21]; const float* n1b  = (const float*)d_in[22];
    const float* n2s  = (const float*)d_in[23]; const float* n2b  = (const float*)d_in[24];
    const float* n3s  = (const float*)d_in[25]; const float* n3b  = (const float*)d_in[26];

    float* outY = (float*)d_out;
    float* outE = outY + (size_t)NROW * H_;

    float* dh = (float*)d_ws;                        // 128 KB
    short* wp = (short*)((char*)d_ws + 131072);      // packed bf16 weights (576 KB)

    const int oW1 = 0,       oW2 = 49152,   oW3 = 65536,   oW11 = 81920;
    const int oW12 = 131072, oW13 = 147456, oWin = 163840, oWout = 229376;

    PackArgs pa;
    pa.src[0]=W1w;  pa.K[0]=384; pa.off[0]=oW1;
    pa.src[1]=W2w;  pa.K[1]=128; pa.off[1]=oW2;
    pa.src[2]=W3w;  pa.K[2]=128; pa.off[2]=oW3;
    pa.src[3]=W11w; pa.K[3]=384; pa.off[3]=oW11;
    pa.src[4]=W12w; pa.K[4]=128; pa.off[4]=oW12;
    pa.src[5]=W13w; pa.K[5]=128; pa.off[5]=oW13;
    pa.src[6]=Winw; pa.K[6]=128; pa.off[6]=oWin;
    pa.src[7]=Woutw;pa.K[7]=512; pa.off[7]=oWout;

    const int nblk = NROW / 32;   // 6144

    k_pack <<<(PACK_TOTAL + 255)/256, 256, 0, stream>>>(pa, wp);
    k_zero <<<(B_*M_*H_ + 255)/256, 256, 0, stream>>>(dh);
    k_msg  <<<nblk, 256, 0, stream>>>(hY, hE, hV, nn,
                                      wp + oW1, W1b, wp + oW2, W2b, wp + oW3, W3b, dh);
    k_scale<<<(B_*M_*H_ + 255)/256, 256, 0, stream>>>(dh, Ys);
    k_hy   <<<nblk, 256, 0, stream>>>(hY, dh, nn, wp + oWin, Winb, wp + oWout, Woutb,
                                      n1s, n1b, n2s, n2b, outY);
    k_he   <<<nblk, 256, 0, stream>>>(outY, hE, hV,
                                      wp + oW11, W11b, wp + oW12, W12b, wp + oW13, W13b,
                                      n3s, n3b, outE);
}